// Round 10
// baseline (185.766 us; speedup 1.0000x reference)
//
#include <hip/hip_runtime.h>

#define BB 32
#define NN 1024
#define CC 192
#define HH 3
#define DD 64
#define BHND 6291456   // B*H*N*D == B*N*C

typedef __bf16 bf16x8 __attribute__((ext_vector_type(8)));
typedef float  f32x4  __attribute__((ext_vector_type(4)));

// Static device scratch.
__device__ __align__(16) unsigned short g_q  [BHND];        // (b,h,n,d) bf16, pre-scaled by mult(b,h)
__device__ __align__(16) unsigned short g_k  [BHND];        // (b,h,n,d) bf16
__device__ __align__(16) unsigned short g_vt [BHND];        // (b,h,d,n) bf16 (V transposed)
__device__ __align__(16) unsigned short g_ao [BHND];        // (b,n,c) bf16 pre-projection attn out
__device__ __align__(16) unsigned short g_wb [3 * CC * CC]; // qkv_w bf16 (576x192)
__device__ __align__(16) unsigned short g_pwb[CC * CC];     // proj_w bf16 (192x192)
__device__ float g_conf[BB];

__device__ __forceinline__ unsigned short f2b(float f) {  // RNE fp32->bf16
    union { float f; unsigned int i; } z; z.f = f;
    return (unsigned short)((z.i + 0x7fffu + ((z.i >> 16) & 1u)) >> 16);
}

// ---------------- Weight convert (fp32 -> bf16) + conf zero ----------------
__global__ __launch_bounds__(256) void convert_kernel(
    const float* __restrict__ qw, const float* __restrict__ pw)
{
    const int i = blockIdx.x * 256 + threadIdx.x;   // float4 index
    if (blockIdx.x == 0 && threadIdx.x < BB) g_conf[threadIdx.x] = 0.0f;
    float4 v; unsigned short* dst;
    if (i < 27648) { v = ((const float4*)qw)[i];         dst = g_wb  + i * 4; }
    else           { v = ((const float4*)pw)[i - 27648]; dst = g_pwb + (i - 27648) * 4; }
    const unsigned int a = (unsigned int)f2b(v.x) | ((unsigned int)f2b(v.y) << 16);
    const unsigned int b = (unsigned int)f2b(v.z) | ((unsigned int)f2b(v.w) << 16);
    *(uint2*)dst = make_uint2(a, b);
}

// ---------------- QKV projection: MFMA, col-split grid -------------------
// grid = 768 = 256 row-groups x 3 col-groups (0:Q, 1:K, 2:V).
__global__ __launch_bounds__(256) void qkv_kernel(
    const float* __restrict__ x,
    const float* __restrict__ bias,
    const float* __restrict__ tp,
    const float* __restrict__ ta)
{
    const int tid  = threadIdx.x;
    const int wv   = tid >> 6;
    const int lane = tid & 63;
    const int q    = lane >> 4;
    const int mq   = lane & 15;
    const int rg   = blockIdx.x / 3;
    const int cg   = blockIdx.x - rg * 3;
    const int base = rg * 128;
    const int r0a  = base + wv * 16;        // strip 0
    const int r0b  = r0a + 64;              // strip 1
    const int b    = base >> 10;

    bf16x8 af0[6], af1[6];
    #pragma unroll
    for (int kh = 0; kh < 6; ++kh) {
        #pragma unroll
        for (int s = 0; s < 2; ++s) {
            const int row = (s ? r0b : r0a) + mq;
            const float4 u0 = *(const float4*)(x + (size_t)row * CC + kh * 32 + q * 8);
            const float4 u1 = *(const float4*)(x + (size_t)row * CC + kh * 32 + q * 8 + 4);
            union { bf16x8 v; unsigned short s_[8]; } t;
            t.s_[0] = f2b(u0.x); t.s_[1] = f2b(u0.y); t.s_[2] = f2b(u0.z); t.s_[3] = f2b(u0.w);
            t.s_[4] = f2b(u1.x); t.s_[5] = f2b(u1.y); t.s_[6] = f2b(u1.z); t.s_[7] = f2b(u1.w);
            if (s) af1[kh] = t.v; else af0[kh] = t.v;
        }
    }

    const int wrow0 = cg * 192;   // W row base for this col-group

    bf16x8 bcur[6];
    #pragma unroll
    for (int kh = 0; kh < 6; ++kh)
        bcur[kh] = *(const bf16x8*)(g_wb + (size_t)(wrow0 + mq) * CC + kh * 32 + q * 8);

    if (cg < 2) {
        float mult_h[HH];
        if (cg == 0) {
            #pragma unroll
            for (int h = 0; h < HH; ++h) {
                const float tau_e = (0.1f + logf(1.0f + __expf(tp[h]))) * 1.5f; // anneal=1.5
                mult_h[h] = 0.125f / (ta[b * 3 + h] + tau_e);
            }
        }
        unsigned short* gout = cg == 0 ? g_q : g_k;
        #pragma unroll 2
        for (int ot = 0; ot < 12; ++ot) {
            const int o0 = ot * 16;
            bf16x8 bnxt[6];
            if (ot < 11) {
                #pragma unroll
                for (int kh = 0; kh < 6; ++kh)
                    bnxt[kh] = *(const bf16x8*)(g_wb + (size_t)(wrow0 + o0 + 16 + mq) * CC + kh * 32 + q * 8);
            }
            f32x4 acc0 = (f32x4){0.f,0.f,0.f,0.f}, acc1 = (f32x4){0.f,0.f,0.f,0.f};
            #pragma unroll
            for (int kh = 0; kh < 6; ++kh) {
                acc0 = __builtin_amdgcn_mfma_f32_16x16x32_bf16(af0[kh], bcur[kh], acc0, 0, 0, 0);
                acc1 = __builtin_amdgcn_mfma_f32_16x16x32_bf16(af1[kh], bcur[kh], acc1, 0, 0, 0);
            }
            const float bv = bias[wrow0 + o0 + mq];
            const int h = o0 >> 6, d0 = o0 & 63;
            const float m = cg == 0 ? mult_h[h] : 1.0f;
            unsigned short* d0p = gout + ((size_t)((b * 3 + h) * NN + (r0a & 1023) + q * 4)) * DD + d0 + mq;
            unsigned short* d1p = gout + ((size_t)((b * 3 + h) * NN + (r0b & 1023) + q * 4)) * DD + d0 + mq;
            #pragma unroll
            for (int r = 0; r < 4; ++r) {
                d0p[(size_t)r * DD] = f2b((acc0[r] + bv) * m);
                d1p[(size_t)r * DD] = f2b((acc1[r] + bv) * m);
            }
            #pragma unroll
            for (int kh = 0; kh < 6; ++kh) bcur[kh] = bnxt[kh];
        }
    } else {
        // ---- V: swapped operands -> transposed D, coalesced g_vt stores ----
        #pragma unroll 2
        for (int ot = 0; ot < 12; ++ot) {
            const int dd0 = ot * 16;
            bf16x8 bnxt[6];
            if (ot < 11) {
                #pragma unroll
                for (int kh = 0; kh < 6; ++kh)
                    bnxt[kh] = *(const bf16x8*)(g_wb + (size_t)(384 + dd0 + 16 + mq) * CC + kh * 32 + q * 8);
            }
            f32x4 acc0 = (f32x4){0.f,0.f,0.f,0.f}, acc1 = (f32x4){0.f,0.f,0.f,0.f};
            #pragma unroll
            for (int kh = 0; kh < 6; ++kh) {
                acc0 = __builtin_amdgcn_mfma_f32_16x16x32_bf16(bcur[kh], af0[kh], acc0, 0, 0, 0);
                acc1 = __builtin_amdgcn_mfma_f32_16x16x32_bf16(bcur[kh], af1[kh], acc1, 0, 0, 0);
            }
            #pragma unroll
            for (int r = 0; r < 4; ++r) {
                const int dd = dd0 + q * 4 + r;
                const int h = dd >> 6, d = dd & 63;
                const float bv = bias[384 + dd];
                g_vt[((size_t)((b * 3 + h) * DD + d)) * NN + (r0a & 1023) + mq] = f2b(acc0[r] + bv);
                g_vt[((size_t)((b * 3 + h) * DD + d)) * NN + (r0b & 1023) + mq] = f2b(acc1[r] + bv);
            }
            #pragma unroll
            for (int kh = 0; kh < 6; ++kh) bcur[kh] = bnxt[kh];
        }
    }
}

// ---------------- Attention: MFMA flash, XCD-pinned, r8 LDS discipline ----
// grid = 768. Swizzle: all 8 q-tiles of one (b,h) share blockIdx%8 (XCD pin).
// Dual per-strip P-tile regions, dedicated conf_s, ONE lgkmcnt(0) per tile.
__global__ __launch_bounds__(256, 3) void attn_kernel(
    const float* __restrict__ dl)
{
    const int tid  = threadIdx.x;
    const int wv   = tid >> 6;
    const int lane = tid & 63;
    const int q    = lane >> 4;
    const int mq   = lane & 15;

    const int low3 = blockIdx.x & 7;
    const int mid  = blockIdx.x >> 3;       // [0,96)
    const int tile = mid & 7;
    const int bh   = (mid >> 3) * 8 + low3; // bh % 8 == blockIdx % 8
    const int n0   = tile * 128;
    const int b    = bh / 3;
    const int h    = bh - b * 3;
    const float keep = 1.0f - 0.3f / (1.0f + __expf(-dl[h]));

    __shared__ __align__(16) unsigned short ks[2][4096];  // 16 KB
    __shared__ __align__(16) unsigned short vt[2][4096];  // 16 KB
    __shared__ __align__(16) unsigned short pt[8192];     // 16 KB (2 strips)
    __shared__ float conf_s[128];

    // Q fragments for both strips (direct global loads)
    const size_t qra = (size_t)(bh * NN + n0 + wv * 16 + mq) * DD;
    const size_t qrb = qra + (size_t)64 * DD;
    const bf16x8 qfa0 = *(const bf16x8*)(g_q + qra + q * 8);
    const bf16x8 qfa1 = *(const bf16x8*)(g_q + qra + 32 + q * 8);
    const bf16x8 qfb0 = *(const bf16x8*)(g_q + qrb + q * 8);
    const bf16x8 qfb1 = *(const bf16x8*)(g_q + qrb + 32 + q * 8);

    // prefetch K/V tile 0
    const size_t krow0 = (size_t)(bh * NN + wv * 16 + mq) * DD;
    const size_t vrow  = (size_t)(bh * DD + wv * 16 + mq) * NN;
    bf16x8 kr0 = *(const bf16x8*)(g_k + krow0 + q * 8);
    bf16x8 kr1 = *(const bf16x8*)(g_k + krow0 + 32 + q * 8);
    bf16x8 vr0 = *(const bf16x8*)(g_vt + vrow + q * 8);
    bf16x8 vr1 = *(const bf16x8*)(g_vt + vrow + 32 + q * 8);

    f32x4 oa[4], ob[4];
    #pragma unroll
    for (int i = 0; i < 4; ++i) { oa[i] = (f32x4){0.f,0.f,0.f,0.f}; ob[i] = (f32x4){0.f,0.f,0.f,0.f}; }
    float la = 0.0f, lb = 0.0f, pma = 0.0f, pmb = 0.0f;

    for (int it = 0; it < 16; ++it) {
        const int cur = it & 1;
        ((bf16x8*)ks[cur])[tid]       = kr0;
        ((bf16x8*)ks[cur])[256 + tid] = kr1;
        ((bf16x8*)vt[cur])[tid]       = vr0;
        ((bf16x8*)vt[cur])[256 + tid] = vr1;
        if (it < 15) {
            const int t1 = (it + 1) * 64;
            kr0 = *(const bf16x8*)(g_k + krow0 + (size_t)t1 * DD + q * 8);
            kr1 = *(const bf16x8*)(g_k + krow0 + (size_t)t1 * DD + 32 + q * 8);
            vr0 = *(const bf16x8*)(g_vt + vrow + t1 + q * 8);
            vr1 = *(const bf16x8*)(g_vt + vrow + t1 + 32 + q * 8);
        }
        __syncthreads();   // buf[cur] visible; compute(it-2) provably done

        // ---- S^T = K . Q^T for both strips (afr shared) ----
        f32x4 sa[4], sb[4];
        #pragma unroll
        for (int i = 0; i < 4; ++i) { sa[i] = (f32x4){0.f,0.f,0.f,0.f}; sb[i] = (f32x4){0.f,0.f,0.f,0.f}; }
        #pragma unroll
        for (int kh = 0; kh < 2; ++kh) {
            const bf16x8 qfa = kh ? qfa1 : qfa0;
            const bf16x8 qfb = kh ? qfb1 : qfb0;
            #pragma unroll
            for (int kt = 0; kt < 4; ++kt) {
                const bf16x8 afr = ((const bf16x8*)ks[cur])[kh * 256 + kt * 64 + lane];
                sa[kt] = __builtin_amdgcn_mfma_f32_16x16x32_bf16(afr, qfa, sa[kt], 0, 0, 0);
                sb[kt] = __builtin_amdgcn_mfma_f32_16x16x32_bf16(afr, qfb, sb[kt], 0, 0, 0);
            }
        }

        // ---- p = exp(s); per-lane max/sum; pack both strips, ONE waitcnt ----
        #pragma unroll
        for (int s = 0; s < 2; ++s) {
            unsigned short* ptb = pt + s * 4096;
            #pragma unroll
            for (int kt = 0; kt < 4; ++kt) {
                const f32x4 sv = s ? sb[kt] : sa[kt];
                const float p0 = __expf(sv[0]);
                const float p1 = __expf(sv[1]);
                const float p2 = __expf(sv[2]);
                const float p3 = __expf(sv[3]);
                const float mx = fmaxf(fmaxf(p0, p1), fmaxf(p2, p3));
                if (s) { pmb = fmaxf(pmb, mx); lb += (p0 + p1) + (p2 + p3); }
                else   { pma = fmaxf(pma, mx); la += (p0 + p1) + (p2 + p3); }
                const unsigned int ua = (__float_as_uint(p0) >> 16) | (__float_as_uint(p1) & 0xffff0000u);
                const unsigned int ub = (__float_as_uint(p2) >> 16) | (__float_as_uint(p3) & 0xffff0000u);
                const int kh2   = kt >> 1;
                const int qk    = (kt * 2 + (q >> 1)) & 3;
                const int chunk = ((wv * 2 + kh2) * 4 + qk) * 16 + mq;
                *(uint2*)((char*)ptb + chunk * 16 + (q & 1) * 8) = make_uint2(ua, ub);
            }
        }
        __builtin_amdgcn_s_waitcnt(0xC07F);   // lgkmcnt(0): own-wave pt visibility

        // ---- O += P V for both strips (vf shared) ----
        #pragma unroll
        for (int kh = 0; kh < 2; ++kh) {
            const bf16x8 pfa = ((const bf16x8*)pt)[(wv * 2 + kh) * 64 + lane];
            const bf16x8 pfb = ((const bf16x8*)(pt + 4096))[(wv * 2 + kh) * 64 + lane];
            #pragma unroll
            for (int ctv = 0; ctv < 4; ++ctv) {
                const bf16x8 vf = ((const bf16x8*)vt[cur])[kh * 256 + ctv * 64 + lane];
                oa[ctv] = __builtin_amdgcn_mfma_f32_16x16x32_bf16(pfa, vf, oa[ctv], 0, 0, 0);
                ob[ctv] = __builtin_amdgcn_mfma_f32_16x16x32_bf16(pfb, vf, ob[ctv], 0, 0, 0);
            }
        }
    }

    // ---- reductions over quads (lane owns query row mq of each strip) ----
    float l0 = la, l1 = lb;
    l0 += __shfl_xor(l0, 16, 64); l0 += __shfl_xor(l0, 32, 64);
    l1 += __shfl_xor(l1, 16, 64); l1 += __shfl_xor(l1, 32, 64);
    float p0 = pma, p1 = pmb;
    p0 = fmaxf(p0, __shfl_xor(p0, 16, 64)); p0 = fmaxf(p0, __shfl_xor(p0, 32, 64));
    p1 = fmaxf(p1, __shfl_xor(p1, 16, 64)); p1 = fmaxf(p1, __shfl_xor(p1, 32, 64));
    const float invla = 1.0f / l0;
    const float invlb = 1.0f / l1;

    if (lane < 16) {
        conf_s[wv * 16 + mq]      = p0 * invla;
        conf_s[64 + wv * 16 + mq] = p1 * invlb;
    }
    __syncthreads();
    if (tid < 64) {
        float v = conf_s[tid] + conf_s[64 + tid];
        #pragma unroll
        for (int off = 1; off <= 32; off <<= 1) v += __shfl_xor(v, off, 64);
        if (tid == 0) atomicAdd(&g_conf[b], v);
    }

    // ---- epilogue per strip ----
    #pragma unroll
    for (int s = 0; s < 2; ++s) {
        const float invl = s ? invlb : invla;
        float sc[4];
        #pragma unroll
        for (int r = 0; r < 4; ++r)
            sc[r] = keep * __int_as_float(
                __builtin_amdgcn_ds_bpermute((q * 4 + r) << 2, __float_as_int(invl)));
        #pragma unroll
        for (int ctv = 0; ctv < 4; ++ctv)
            #pragma unroll
            for (int r = 0; r < 4; ++r) {
                const f32x4 o = s ? ob[ctv] : oa[ctv];
                g_ao[((size_t)(b * NN + n0 + s * 64 + wv * 16 + q * 4 + r)) * CC + h * DD + ctv * 16 + mq] =
                    f2b(o[r] * sc[r]);
            }
    }
}

// ---------------- Projection + residual + conf finalize: col-split --------
// grid = 512 = 256 row-groups x 2 col-groups (6 col-tiles each).
__global__ __launch_bounds__(256) void proj_kernel(
    const float* __restrict__ pb,
    const float* __restrict__ rp,
    const float* __restrict__ x,
    float* __restrict__ out,
    float* __restrict__ out_c)
{
    const int tid  = threadIdx.x;
    const int wv   = tid >> 6;
    const int lane = tid & 63;
    const int q    = lane >> 4;
    const int mq   = lane & 15;
    const int rg   = blockIdx.x >> 1;
    const int cg   = blockIdx.x & 1;
    const int base = rg * 128;
    const int r0a  = base + wv * 16;
    const int r0b  = r0a + 64;
    const int ob0  = cg * 96;              // output col base

    if (blockIdx.x == 0 && tid < BB)
        out_c[tid] = g_conf[tid] * (1.0f / (float)(HH * NN));   // attn complete

    const float wres = 1.0f / (1.0f + __expf(-rp[0]));

    bf16x8 af0[6], af1[6];
    #pragma unroll
    for (int kh = 0; kh < 6; ++kh) {
        af0[kh] = *(const bf16x8*)(g_ao + (size_t)(r0a + mq) * CC + kh * 32 + q * 8);
        af1[kh] = *(const bf16x8*)(g_ao + (size_t)(r0b + mq) * CC + kh * 32 + q * 8);
    }

    bf16x8 bcur[6];
    #pragma unroll
    for (int kh = 0; kh < 6; ++kh)
        bcur[kh] = *(const bf16x8*)(g_pwb + (size_t)(ob0 + mq) * CC + kh * 32 + q * 8);
    #pragma unroll 2
    for (int ot = 0; ot < 6; ++ot) {
        const int o0 = ob0 + ot * 16;
        bf16x8 bnxt[6];
        if (ot < 5) {
            #pragma unroll
            for (int kh = 0; kh < 6; ++kh)
                bnxt[kh] = *(const bf16x8*)(g_pwb + (size_t)(o0 + 16 + mq) * CC + kh * 32 + q * 8);
        }
        f32x4 acc0 = (f32x4){0.f,0.f,0.f,0.f}, acc1 = (f32x4){0.f,0.f,0.f,0.f};
        #pragma unroll
        for (int kh = 0; kh < 6; ++kh) {
            acc0 = __builtin_amdgcn_mfma_f32_16x16x32_bf16(af0[kh], bcur[kh], acc0, 0, 0, 0);
            acc1 = __builtin_amdgcn_mfma_f32_16x16x32_bf16(af1[kh], bcur[kh], acc1, 0, 0, 0);
        }
        const float bv = pb[o0 + mq];
        #pragma unroll
        for (int r = 0; r < 4; ++r) {
            const int na = r0a + q * 4 + r;
            const int nb = r0b + q * 4 + r;
            const float xa = x[(size_t)na * CC + o0 + mq];
            const float xb = x[(size_t)nb * CC + o0 + mq];
            out[(size_t)na * CC + o0 + mq] = wres * (acc0[r] + bv) + (1.0f - wres) * xa;
            out[(size_t)nb * CC + o0 + mq] = wres * (acc1[r] + bv) + (1.0f - wres) * xb;
        }
        #pragma unroll
        for (int kh = 0; kh < 6; ++kh) bcur[kh] = bnxt[kh];
    }
}

extern "C" void kernel_launch(void* const* d_in, const int* in_sizes, int n_in,
                              void* d_out, int out_size, void* d_ws, size_t ws_size,
                              hipStream_t stream)
{
    const float* x  = (const float*)d_in[0];
    const float* qw = (const float*)d_in[1];
    const float* qb = (const float*)d_in[2];
    const float* pw = (const float*)d_in[3];
    const float* pb = (const float*)d_in[4];
    const float* tp = (const float*)d_in[5];
    const float* dl = (const float*)d_in[6];
    const float* rp = (const float*)d_in[7];
    const float* ta = (const float*)d_in[8];

    float* out   = (float*)d_out;
    float* out_c = out + (size_t)BB * NN * CC;

    convert_kernel<<<144, 256, 0, stream>>>(qw, pw);
    qkv_kernel<<<(BB * NN) / 128 * 3, 256, 0, stream>>>(x, qb, tp, ta);
    attn_kernel<<<BB * HH * (NN / 128), 256, 0, stream>>>(dl);
    proj_kernel<<<(BB * NN) / 128 * 2, 256, 0, stream>>>(pb, rp, x, out, out_c);
}

// Round 11
// 185.413 us; speedup vs baseline: 1.0019x; 1.0019x over previous
//
#include <hip/hip_runtime.h>

#define BB 32
#define NN 1024
#define CC 192
#define HH 3
#define DD 64
#define BHND 6291456   // B*H*N*D == B*N*C

typedef __bf16 bf16x8 __attribute__((ext_vector_type(8)));
typedef float  f32x4  __attribute__((ext_vector_type(4)));

// Static device scratch.
__device__ __align__(16) unsigned short g_xb [BHND];        // x in bf16 (b,n,c)
__device__ __align__(16) unsigned short g_q  [BHND];        // (b,h,n,d) bf16, pre-scaled by mult(b,h)
__device__ __align__(16) unsigned short g_k  [BHND];        // (b,h,n,d) bf16
__device__ __align__(16) unsigned short g_vt [BHND];        // (b,h,d,n) bf16 (V transposed)
__device__ __align__(16) unsigned short g_ao [BHND];        // (b,n,c) bf16 pre-projection attn out
__device__ __align__(16) unsigned short g_wb [3 * CC * CC]; // qkv_w bf16 (576x192)
__device__ __align__(16) unsigned short g_pwb[CC * CC];     // proj_w bf16 (192x192)
__device__ float g_conf[BB];

__device__ __forceinline__ unsigned short f2b(float f) {  // RNE fp32->bf16
    union { float f; unsigned int i; } z; z.f = f;
    return (unsigned short)((z.i + 0x7fffu + ((z.i >> 16) & 1u)) >> 16);
}

// ------------- Convert x + weights (fp32 -> bf16) + conf zero --------------
// grid = 6288 x 256: i in [0, 1572864) -> x, then 27648 qkv_w, then 9216 proj_w.
__global__ __launch_bounds__(256) void convert_kernel(
    const float* __restrict__ x,
    const float* __restrict__ qw, const float* __restrict__ pw)
{
    const int i = blockIdx.x * 256 + threadIdx.x;   // float4 index
    if (blockIdx.x == 0 && threadIdx.x < BB) g_conf[threadIdx.x] = 0.0f;
    float4 v; unsigned short* dst;
    if (i < 1572864)      { v = ((const float4*)x)[i];            dst = g_xb  + i * 4; }
    else if (i < 1600512) { v = ((const float4*)qw)[i - 1572864]; dst = g_wb  + (i - 1572864) * 4; }
    else                  { v = ((const float4*)pw)[i - 1600512]; dst = g_pwb + (i - 1600512) * 4; }
    const unsigned int a = (unsigned int)f2b(v.x) | ((unsigned int)f2b(v.y) << 16);
    const unsigned int b = (unsigned int)f2b(v.z) | ((unsigned int)f2b(v.w) << 16);
    *(uint2*)dst = make_uint2(a, b);
}

// ---------------- QKV projection: MFMA, col-split grid, bf16 x ------------
// grid = 768 = 256 row-groups x 3 col-groups (0:Q, 1:K, 2:V).
__global__ __launch_bounds__(256) void qkv_kernel(
    const float* __restrict__ bias,
    const float* __restrict__ tp,
    const float* __restrict__ ta)
{
    const int tid  = threadIdx.x;
    const int wv   = tid >> 6;
    const int lane = tid & 63;
    const int q    = lane >> 4;
    const int mq   = lane & 15;
    const int rg   = blockIdx.x / 3;
    const int cg   = blockIdx.x - rg * 3;
    const int base = rg * 128;
    const int r0a  = base + wv * 16;        // strip 0
    const int r0b  = r0a + 64;              // strip 1
    const int b    = base >> 10;

    // A-frags: direct bf16 loads (no cvt chain)
    bf16x8 af0[6], af1[6];
    #pragma unroll
    for (int kh = 0; kh < 6; ++kh) {
        af0[kh] = *(const bf16x8*)(g_xb + (size_t)(r0a + mq) * CC + kh * 32 + q * 8);
        af1[kh] = *(const bf16x8*)(g_xb + (size_t)(r0b + mq) * CC + kh * 32 + q * 8);
    }

    const int wrow0 = cg * 192;   // W row base for this col-group

    bf16x8 bcur[6];
    #pragma unroll
    for (int kh = 0; kh < 6; ++kh)
        bcur[kh] = *(const bf16x8*)(g_wb + (size_t)(wrow0 + mq) * CC + kh * 32 + q * 8);

    if (cg < 2) {
        float mult_h[HH];
        if (cg == 0) {
            #pragma unroll
            for (int h = 0; h < HH; ++h) {
                const float tau_e = (0.1f + logf(1.0f + __expf(tp[h]))) * 1.5f; // anneal=1.5
                mult_h[h] = 0.125f / (ta[b * 3 + h] + tau_e);
            }
        }
        unsigned short* gout = cg == 0 ? g_q : g_k;
        #pragma unroll 2
        for (int ot = 0; ot < 12; ++ot) {
            const int o0 = ot * 16;
            bf16x8 bnxt[6];
            if (ot < 11) {
                #pragma unroll
                for (int kh = 0; kh < 6; ++kh)
                    bnxt[kh] = *(const bf16x8*)(g_wb + (size_t)(wrow0 + o0 + 16 + mq) * CC + kh * 32 + q * 8);
            }
            f32x4 acc0 = (f32x4){0.f,0.f,0.f,0.f}, acc1 = (f32x4){0.f,0.f,0.f,0.f};
            #pragma unroll
            for (int kh = 0; kh < 6; ++kh) {
                acc0 = __builtin_amdgcn_mfma_f32_16x16x32_bf16(af0[kh], bcur[kh], acc0, 0, 0, 0);
                acc1 = __builtin_amdgcn_mfma_f32_16x16x32_bf16(af1[kh], bcur[kh], acc1, 0, 0, 0);
            }
            const float bv = bias[wrow0 + o0 + mq];
            const int h = o0 >> 6, d0 = o0 & 63;
            const float m = cg == 0 ? mult_h[h] : 1.0f;
            unsigned short* d0p = gout + ((size_t)((b * 3 + h) * NN + (r0a & 1023) + q * 4)) * DD + d0 + mq;
            unsigned short* d1p = gout + ((size_t)((b * 3 + h) * NN + (r0b & 1023) + q * 4)) * DD + d0 + mq;
            #pragma unroll
            for (int r = 0; r < 4; ++r) {
                d0p[(size_t)r * DD] = f2b((acc0[r] + bv) * m);
                d1p[(size_t)r * DD] = f2b((acc1[r] + bv) * m);
            }
            #pragma unroll
            for (int kh = 0; kh < 6; ++kh) bcur[kh] = bnxt[kh];
        }
    } else {
        // ---- V: swapped operands -> transposed D, coalesced g_vt stores ----
        #pragma unroll 2
        for (int ot = 0; ot < 12; ++ot) {
            const int dd0 = ot * 16;
            bf16x8 bnxt[6];
            if (ot < 11) {
                #pragma unroll
                for (int kh = 0; kh < 6; ++kh)
                    bnxt[kh] = *(const bf16x8*)(g_wb + (size_t)(384 + dd0 + 16 + mq) * CC + kh * 32 + q * 8);
            }
            f32x4 acc0 = (f32x4){0.f,0.f,0.f,0.f}, acc1 = (f32x4){0.f,0.f,0.f,0.f};
            #pragma unroll
            for (int kh = 0; kh < 6; ++kh) {
                acc0 = __builtin_amdgcn_mfma_f32_16x16x32_bf16(bcur[kh], af0[kh], acc0, 0, 0, 0);
                acc1 = __builtin_amdgcn_mfma_f32_16x16x32_bf16(bcur[kh], af1[kh], acc1, 0, 0, 0);
            }
            #pragma unroll
            for (int r = 0; r < 4; ++r) {
                const int dd = dd0 + q * 4 + r;
                const int h = dd >> 6, d = dd & 63;
                const float bv = bias[384 + dd];
                g_vt[((size_t)((b * 3 + h) * DD + d)) * NN + (r0a & 1023) + mq] = f2b(acc0[r] + bv);
                g_vt[((size_t)((b * 3 + h) * DD + d)) * NN + (r0b & 1023) + mq] = f2b(acc1[r] + bv);
            }
            #pragma unroll
            for (int kh = 0; kh < 6; ++kh) bcur[kh] = bnxt[kh];
        }
    }
}

// ---------------- Attention: MFMA flash, XCD-pinned, r8 LDS discipline ----
__global__ __launch_bounds__(256, 3) void attn_kernel(
    const float* __restrict__ dl)
{
    const int tid  = threadIdx.x;
    const int wv   = tid >> 6;
    const int lane = tid & 63;
    const int q    = lane >> 4;
    const int mq   = lane & 15;

    const int low3 = blockIdx.x & 7;
    const int mid  = blockIdx.x >> 3;       // [0,96)
    const int tile = mid & 7;
    const int bh   = (mid >> 3) * 8 + low3; // bh % 8 == blockIdx % 8
    const int n0   = tile * 128;
    const int b    = bh / 3;
    const int h    = bh - b * 3;
    const float keep = 1.0f - 0.3f / (1.0f + __expf(-dl[h]));

    __shared__ __align__(16) unsigned short ks[2][4096];  // 16 KB
    __shared__ __align__(16) unsigned short vt[2][4096];  // 16 KB
    __shared__ __align__(16) unsigned short pt[8192];     // 16 KB (2 strips)
    __shared__ float conf_s[128];

    const size_t qra = (size_t)(bh * NN + n0 + wv * 16 + mq) * DD;
    const size_t qrb = qra + (size_t)64 * DD;
    const bf16x8 qfa0 = *(const bf16x8*)(g_q + qra + q * 8);
    const bf16x8 qfa1 = *(const bf16x8*)(g_q + qra + 32 + q * 8);
    const bf16x8 qfb0 = *(const bf16x8*)(g_q + qrb + q * 8);
    const bf16x8 qfb1 = *(const bf16x8*)(g_q + qrb + 32 + q * 8);

    const size_t krow0 = (size_t)(bh * NN + wv * 16 + mq) * DD;
    const size_t vrow  = (size_t)(bh * DD + wv * 16 + mq) * NN;
    bf16x8 kr0 = *(const bf16x8*)(g_k + krow0 + q * 8);
    bf16x8 kr1 = *(const bf16x8*)(g_k + krow0 + 32 + q * 8);
    bf16x8 vr0 = *(const bf16x8*)(g_vt + vrow + q * 8);
    bf16x8 vr1 = *(const bf16x8*)(g_vt + vrow + 32 + q * 8);

    f32x4 oa[4], ob[4];
    #pragma unroll
    for (int i = 0; i < 4; ++i) { oa[i] = (f32x4){0.f,0.f,0.f,0.f}; ob[i] = (f32x4){0.f,0.f,0.f,0.f}; }
    float la = 0.0f, lb = 0.0f, pma = 0.0f, pmb = 0.0f;

    for (int it = 0; it < 16; ++it) {
        const int cur = it & 1;
        ((bf16x8*)ks[cur])[tid]       = kr0;
        ((bf16x8*)ks[cur])[256 + tid] = kr1;
        ((bf16x8*)vt[cur])[tid]       = vr0;
        ((bf16x8*)vt[cur])[256 + tid] = vr1;
        if (it < 15) {
            const int t1 = (it + 1) * 64;
            kr0 = *(const bf16x8*)(g_k + krow0 + (size_t)t1 * DD + q * 8);
            kr1 = *(const bf16x8*)(g_k + krow0 + (size_t)t1 * DD + 32 + q * 8);
            vr0 = *(const bf16x8*)(g_vt + vrow + t1 + q * 8);
            vr1 = *(const bf16x8*)(g_vt + vrow + t1 + 32 + q * 8);
        }
        __syncthreads();   // buf[cur] visible; compute(it-2) provably done

        f32x4 sa[4], sb[4];
        #pragma unroll
        for (int i = 0; i < 4; ++i) { sa[i] = (f32x4){0.f,0.f,0.f,0.f}; sb[i] = (f32x4){0.f,0.f,0.f,0.f}; }
        #pragma unroll
        for (int kh = 0; kh < 2; ++kh) {
            const bf16x8 qfa = kh ? qfa1 : qfa0;
            const bf16x8 qfb = kh ? qfb1 : qfb0;
            #pragma unroll
            for (int kt = 0; kt < 4; ++kt) {
                const bf16x8 afr = ((const bf16x8*)ks[cur])[kh * 256 + kt * 64 + lane];
                sa[kt] = __builtin_amdgcn_mfma_f32_16x16x32_bf16(afr, qfa, sa[kt], 0, 0, 0);
                sb[kt] = __builtin_amdgcn_mfma_f32_16x16x32_bf16(afr, qfb, sb[kt], 0, 0, 0);
            }
        }

        #pragma unroll
        for (int s = 0; s < 2; ++s) {
            unsigned short* ptb = pt + s * 4096;
            #pragma unroll
            for (int kt = 0; kt < 4; ++kt) {
                const f32x4 sv = s ? sb[kt] : sa[kt];
                const float p0 = __expf(sv[0]);
                const float p1 = __expf(sv[1]);
                const float p2 = __expf(sv[2]);
                const float p3 = __expf(sv[3]);
                const float mx = fmaxf(fmaxf(p0, p1), fmaxf(p2, p3));
                if (s) { pmb = fmaxf(pmb, mx); lb += (p0 + p1) + (p2 + p3); }
                else   { pma = fmaxf(pma, mx); la += (p0 + p1) + (p2 + p3); }
                const unsigned int ua = (__float_as_uint(p0) >> 16) | (__float_as_uint(p1) & 0xffff0000u);
                const unsigned int ub = (__float_as_uint(p2) >> 16) | (__float_as_uint(p3) & 0xffff0000u);
                const int kh2   = kt >> 1;
                const int qk    = (kt * 2 + (q >> 1)) & 3;
                const int chunk = ((wv * 2 + kh2) * 4 + qk) * 16 + mq;
                *(uint2*)((char*)ptb + chunk * 16 + (q & 1) * 8) = make_uint2(ua, ub);
            }
        }
        __builtin_amdgcn_s_waitcnt(0xC07F);   // lgkmcnt(0): own-wave pt visibility

        #pragma unroll
        for (int kh = 0; kh < 2; ++kh) {
            const bf16x8 pfa = ((const bf16x8*)pt)[(wv * 2 + kh) * 64 + lane];
            const bf16x8 pfb = ((const bf16x8*)(pt + 4096))[(wv * 2 + kh) * 64 + lane];
            #pragma unroll
            for (int ctv = 0; ctv < 4; ++ctv) {
                const bf16x8 vf = ((const bf16x8*)vt[cur])[kh * 256 + ctv * 64 + lane];
                oa[ctv] = __builtin_amdgcn_mfma_f32_16x16x32_bf16(pfa, vf, oa[ctv], 0, 0, 0);
                ob[ctv] = __builtin_amdgcn_mfma_f32_16x16x32_bf16(pfb, vf, ob[ctv], 0, 0, 0);
            }
        }
    }

    float l0 = la, l1 = lb;
    l0 += __shfl_xor(l0, 16, 64); l0 += __shfl_xor(l0, 32, 64);
    l1 += __shfl_xor(l1, 16, 64); l1 += __shfl_xor(l1, 32, 64);
    float p0 = pma, p1 = pmb;
    p0 = fmaxf(p0, __shfl_xor(p0, 16, 64)); p0 = fmaxf(p0, __shfl_xor(p0, 32, 64));
    p1 = fmaxf(p1, __shfl_xor(p1, 16, 64)); p1 = fmaxf(p1, __shfl_xor(p1, 32, 64));
    const float invla = 1.0f / l0;
    const float invlb = 1.0f / l1;

    if (lane < 16) {
        conf_s[wv * 16 + mq]      = p0 * invla;
        conf_s[64 + wv * 16 + mq] = p1 * invlb;
    }
    __syncthreads();
    if (tid < 64) {
        float v = conf_s[tid] + conf_s[64 + tid];
        #pragma unroll
        for (int off = 1; off <= 32; off <<= 1) v += __shfl_xor(v, off, 64);
        if (tid == 0) atomicAdd(&g_conf[b], v);
    }

    #pragma unroll
    for (int s = 0; s < 2; ++s) {
        const float invl = s ? invlb : invla;
        float sc[4];
        #pragma unroll
        for (int r = 0; r < 4; ++r)
            sc[r] = keep * __int_as_float(
                __builtin_amdgcn_ds_bpermute((q * 4 + r) << 2, __float_as_int(invl)));
        #pragma unroll
        for (int ctv = 0; ctv < 4; ++ctv)
            #pragma unroll
            for (int r = 0; r < 4; ++r) {
                const f32x4 o = s ? ob[ctv] : oa[ctv];
                g_ao[((size_t)(b * NN + n0 + s * 64 + wv * 16 + q * 4 + r)) * CC + h * DD + ctv * 16 + mq] =
                    f2b(o[r] * sc[r]);
            }
    }
}

// ---------------- Projection + residual + conf finalize: col-split --------
__global__ __launch_bounds__(256) void proj_kernel(
    const float* __restrict__ pb,
    const float* __restrict__ rp,
    const float* __restrict__ x,
    float* __restrict__ out,
    float* __restrict__ out_c)
{
    const int tid  = threadIdx.x;
    const int wv   = tid >> 6;
    const int lane = tid & 63;
    const int q    = lane >> 4;
    const int mq   = lane & 15;
    const int rg   = blockIdx.x >> 1;
    const int cg   = blockIdx.x & 1;
    const int base = rg * 128;
    const int r0a  = base + wv * 16;
    const int r0b  = r0a + 64;
    const int ob0  = cg * 96;              // output col base

    if (blockIdx.x == 0 && tid < BB)
        out_c[tid] = g_conf[tid] * (1.0f / (float)(HH * NN));   // attn complete

    const float wres = 1.0f / (1.0f + __expf(-rp[0]));

    bf16x8 af0[6], af1[6];
    #pragma unroll
    for (int kh = 0; kh < 6; ++kh) {
        af0[kh] = *(const bf16x8*)(g_ao + (size_t)(r0a + mq) * CC + kh * 32 + q * 8);
        af1[kh] = *(const bf16x8*)(g_ao + (size_t)(r0b + mq) * CC + kh * 32 + q * 8);
    }

    bf16x8 bcur[6];
    #pragma unroll
    for (int kh = 0; kh < 6; ++kh)
        bcur[kh] = *(const bf16x8*)(g_pwb + (size_t)(ob0 + mq) * CC + kh * 32 + q * 8);
    #pragma unroll 2
    for (int ot = 0; ot < 6; ++ot) {
        const int o0 = ob0 + ot * 16;
        bf16x8 bnxt[6];
        if (ot < 5) {
            #pragma unroll
            for (int kh = 0; kh < 6; ++kh)
                bnxt[kh] = *(const bf16x8*)(g_pwb + (size_t)(o0 + 16 + mq) * CC + kh * 32 + q * 8);
        }
        f32x4 acc0 = (f32x4){0.f,0.f,0.f,0.f}, acc1 = (f32x4){0.f,0.f,0.f,0.f};
        #pragma unroll
        for (int kh = 0; kh < 6; ++kh) {
            acc0 = __builtin_amdgcn_mfma_f32_16x16x32_bf16(af0[kh], bcur[kh], acc0, 0, 0, 0);
            acc1 = __builtin_amdgcn_mfma_f32_16x16x32_bf16(af1[kh], bcur[kh], acc1, 0, 0, 0);
        }
        const float bv = pb[o0 + mq];
        #pragma unroll
        for (int r = 0; r < 4; ++r) {
            const int na = r0a + q * 4 + r;
            const int nb = r0b + q * 4 + r;
            const float xa = x[(size_t)na * CC + o0 + mq];
            const float xb = x[(size_t)nb * CC + o0 + mq];
            out[(size_t)na * CC + o0 + mq] = wres * (acc0[r] + bv) + (1.0f - wres) * xa;
            out[(size_t)nb * CC + o0 + mq] = wres * (acc1[r] + bv) + (1.0f - wres) * xb;
        }
        #pragma unroll
        for (int kh = 0; kh < 6; ++kh) bcur[kh] = bnxt[kh];
    }
}

extern "C" void kernel_launch(void* const* d_in, const int* in_sizes, int n_in,
                              void* d_out, int out_size, void* d_ws, size_t ws_size,
                              hipStream_t stream)
{
    const float* x  = (const float*)d_in[0];
    const float* qw = (const float*)d_in[1];
    const float* qb = (const float*)d_in[2];
    const float* pw = (const float*)d_in[3];
    const float* pb = (const float*)d_in[4];
    const float* tp = (const float*)d_in[5];
    const float* dl = (const float*)d_in[6];
    const float* rp = (const float*)d_in[7];
    const float* ta = (const float*)d_in[8];

    float* out   = (float*)d_out;
    float* out_c = out + (size_t)BB * NN * CC;

    convert_kernel<<<6288, 256, 0, stream>>>(x, qw, pw);
    qkv_kernel<<<(BB * NN) / 128 * 3, 256, 0, stream>>>(qb, tp, ta);
    attn_kernel<<<BB * HH * (NN / 128), 256, 0, stream>>>(dl);
    proj_kernel<<<(BB * NN) / 128 * 2, 256, 0, stream>>>(pb, rp, x, out, out_c);
}